// Round 18
// baseline (1937.681 us; speedup 1.0000x reference)
//
#include <hip/hip_runtime.h>

// ---------------------------------------------------------------------------
// BiLSTM (T=784, B=512, H=200, D=1) on MI355X — round 18.
//
// Round-17 CONFIRMED: region serialization was the stall (1636->1409us via
// phase-split: all MFMA issue, then all cell chains). Remaining ~2000cy/step
// is dependent-chain latency that 2 waves/SIMD can't fill. Round 18 trades
// registers for occupancy: 12 waves (768 thr, launch_bounds(768,3) -> 3
// waves/SIMD, 170 regs/wave). Per wave 3 AGPR tiles (a0..a83) + 1-2 LDS
// tiles; 36 AGPR + 14 LDS = 50 tiles CU-resident. Per-SIMD issue work
// unchanged; 3rd wave fills stalls (precedent: 1->2 waves = -20%, r5->r7).
// Keeps all r17 wins: phase-split, prescaled weights (exp2-ready gates),
// v_cvt_pk_bf16_f32, block-private fire-and-forget hpart stores, lgkm-only
// barrier, input path folded into K-pad slots 200..204.
// ---------------------------------------------------------------------------

typedef short short8 __attribute__((ext_vector_type(8)));
typedef float f32x4 __attribute__((ext_vector_type(4)));
typedef unsigned short ushort_t;

#define T_STEPS 784
#define BATCH   512
#define HID     200
#define NKT     7
#define NMT     50
#define THREADS 768   // 12 waves, 3 waves/SIMD
#define HBUF    3584
#define NLDST   14    // LDS-resident tiles 36..49
#define DYN_LDS (2 * HBUF * 2 + NLDST * NKT * 512 * 2)  // 14336+100352=114688

// ws layout (bytes)
#define WS_HPART 0                                       // 784*64*200*4
#define WS_UV    (40140800)                              // 12,800
#define WS_WSW   (40140800 + 12800)                      // 716,800

#define ACLOB \
  "a0","a1","a2","a3","a4","a5","a6","a7","a8","a9","a10","a11","a12","a13", \
  "a14","a15","a16","a17","a18","a19","a20","a21","a22","a23","a24","a25",   \
  "a26","a27","a28","a29","a30","a31","a32","a33","a34","a35","a36","a37",   \
  "a38","a39","a40","a41","a42","a43","a44","a45","a46","a47","a48","a49",   \
  "a50","a51","a52","a53","a54","a55","a56","a57","a58","a59","a60","a61",   \
  "a62","a63","a64","a65","a66","a67","a68","a69","a70","a71","a72","a73",   \
  "a74","a75","a76","a77","a78","a79","a80","a81","a82","a83"

#define L1E 1.44269504088896340736f  // log2(e)

__device__ __forceinline__ ushort_t f2bf(float f) {
  union { float f; unsigned u; } x; x.f = f;
  return (ushort_t)((x.u + 0x7FFFu + ((x.u >> 16) & 1u)) >> 16);  // RNE
}
__device__ __forceinline__ float bf2f(ushort_t u) {
  union { unsigned u; float f; } x; x.u = (unsigned)u << 16; return x.f;
}

__device__ __forceinline__ float row16_sum(float v) {
  union { float f; int i; } a, b;
  a.f = v;
  b.i = __builtin_amdgcn_update_dpp(0, a.i, 0x118, 0xF, 0xF, true); a.f += b.f;
  b.i = __builtin_amdgcn_update_dpp(0, a.i, 0x114, 0xF, 0xF, true); a.f += b.f;
  b.i = __builtin_amdgcn_update_dpp(0, a.i, 0x112, 0xF, 0xF, true); a.f += b.f;
  b.i = __builtin_amdgcn_update_dpp(0, a.i, 0x111, 0xF, 0xF, true); a.f += b.f;
  return a.f;  // row sum valid at bcol==15
}

// --- AGPR pin: one 4-dword fragment of tile T, k-tile K into fixed a-regs
#define PIN1(T, K, N0, N1, N2, N3)                                            \
  {                                                                           \
    union { short8 s; unsigned u[4]; } cv;                                    \
    cv.s = *(const short8*)(wg +                                              \
        ((size_t)((rbase + (T)) * NKT + (K))) * 512 + lane * 8);              \
    asm volatile("v_accvgpr_write_b32 a" #N0 ", %0\n\t"                       \
                 "v_accvgpr_write_b32 a" #N1 ", %1\n\t"                       \
                 "v_accvgpr_write_b32 a" #N2 ", %2\n\t"                       \
                 "v_accvgpr_write_b32 a" #N3 ", %3"                           \
                 :: "v"(cv.u[0]), "v"(cv.u[1]), "v"(cv.u[2]), "v"(cv.u[3])    \
                 : "a" #N0, "a" #N1, "a" #N2, "a" #N3);                       \
  }

// ---------------------------------------------------------------------------
__global__ void prep_uv(const float* __restrict__ Wih_f, const float* __restrict__ b_f,
                        const float* __restrict__ Wih_b, const float* __restrict__ b_b,
                        const float* __restrict__ W_in, const float* __restrict__ b_in,
                        float* __restrict__ uv_g) {
  const int dir = blockIdx.x, j = threadIdx.x;
  if (j >= HID) return;
  const float* Wih = dir ? Wih_b : Wih_f;
  const float* b   = dir ? b_b   : b_f;
  for (int q = 0; q < 4; ++q) {
    const int row = q * HID + j;
    const float* wr = Wih + (size_t)row * HID;
    float u = 0.f, v = 0.f;
    for (int k = 0; k < HID; ++k) {
      u = fmaf(wr[k], W_in[k], u);
      v = fmaf(wr[k], b_in[k], v);
    }
    uv_g[(size_t)dir * 1600 + j * 8 + q]     = u;
    uv_g[(size_t)dir * 1600 + j * 8 + 4 + q] = v + b[row];
  }
}

// ---------------------------------------------------------------------------
// prep_w: A-fragments, rows pre-scaled by sq = (q==2) ? -2*log2e : -log2e.
// ---------------------------------------------------------------------------
__global__ void prep_w(const float* __restrict__ Whh_f, const float* __restrict__ Whh_b,
                       const float* __restrict__ uv_g, ushort_t* __restrict__ w_sw) {
  const int bid = blockIdx.x, lane = threadIdx.x;
  const int dir = bid / (NMT * NKT);
  const int rem = bid % (NMT * NKT);
  const int mt = rem / NKT, kt = rem % NKT;
  const float* W = dir ? Whh_b : Whh_f;
  const int m = lane & 15;
  const int q = m & 3;
  const int j = mt * 4 + (m >> 2);
  const int row = q * HID + j;
  const int grp = lane >> 4;
  const float sq = (q == 2) ? (-2.f * L1E) : (-L1E);
  short8 v8 = {0, 0, 0, 0, 0, 0, 0, 0};
  if (kt < 6) {
#pragma unroll
    for (int e = 0; e < 8; ++e)
      v8[e] = (short)f2bf(sq * W[(size_t)row * HID + kt * 32 + grp * 8 + e]);
  } else if (grp == 0) {
#pragma unroll
    for (int e = 0; e < 8; ++e)
      v8[e] = (short)f2bf(sq * W[(size_t)row * HID + 192 + e]);
  } else if (grp == 1) {
    const float U = sq * uv_g[(size_t)dir * 1600 + j * 8 + q];
    const float V = sq * uv_g[(size_t)dir * 1600 + j * 8 + 4 + q];
    const ushort_t vhi = f2bf(V), uhi = f2bf(U);
    v8[0] = (short)vhi;
    v8[1] = (short)f2bf(V - bf2f(vhi));
    v8[2] = (short)uhi;
    v8[3] = (short)f2bf(U - bf2f(uhi));
    v8[4] = (short)uhi;
  }
  *(short8*)(w_sw + (size_t)bid * 512 + (size_t)lane * 8) = v8;
}

// ---------------------------------------------------------------------------
// cell update: a[0..3] arrive PRE-SCALED exp2-ready. No gate clamps; ec
// clamp kept (c drifts).
// ---------------------------------------------------------------------------
__device__ __forceinline__ void cell_update(const f32x4 a, const int haddr,
                                            ushort_t* __restrict__ hnext,
                                            float& c, float& hold) {
  const float ei = __builtin_amdgcn_exp2f(a[0]);
  const float ef = __builtin_amdgcn_exp2f(a[1]);
  const float eg = __builtin_amdgcn_exp2f(a[2]);
  const float eo = __builtin_amdgcn_exp2f(a[3]);
  const float pi = 1.f + ei, pf = 1.f + ef, pg = 1.f + eg;
  const float pig = pi * pg;
  const float R1 = __builtin_amdgcn_rcpf(pig * pf);
  const float sf = pig * R1;
  const float sitg = (1.f - eg) * pf * R1;
  const float cn = fmaf(sf, c, sitg);
  c = cn;
  const float ec = __builtin_amdgcn_exp2f(fminf(-2.f * L1E * cn, 83.f));
  const float R2 = __builtin_amdgcn_rcpf((1.f + ec) * (1.f + eo));
  const float h = (1.f - ec) * R2;
  unsigned hu;
  asm("v_cvt_pk_bf16_f32 %0, %1, %2" : "=v"(hu) : "v"(h), "v"(0.f));
  hnext[haddr] = (ushort_t)hu;
  hold = row16_sum(h);
}

// ---------------------------------------------------------------------------
// 784-step scan: 3 AGPR tiles (a0..a83) + NLDS (1/2) LDS tiles per wave.
// Phase 1: all MFMA issue. Phase 2: all cell chains (4-5 way ILP/wave,
// 3 waves/SIMD cross-wave hiding).
// ---------------------------------------------------------------------------
template <int NLDS>
__device__ __forceinline__ void scan_loop(
    const int rbase, const int lfirst, const int dir, const int b0,
    const int lane, const int wv, const int blk, const ushort_t* __restrict__ wg,
    const float* __restrict__ x, float* __restrict__ hpart,
    ushort_t* __restrict__ h_lds, const ushort_t* __restrict__ w_lds_my) {
  constexpr int NREG = 3;
  constexpr int NT = NREG + NLDS;
  const int bcol = lane & 15, krow = lane >> 4;
  const bool xw = (wv == 0) & (krow == 1);

  PIN1(0, 0,  0,  1,  2,  3)  PIN1(0, 1,  4,  5,  6,  7)
  PIN1(0, 2,  8,  9, 10, 11)  PIN1(0, 3, 12, 13, 14, 15)
  PIN1(0, 4, 16, 17, 18, 19)  PIN1(0, 5, 20, 21, 22, 23)
  PIN1(0, 6, 24, 25, 26, 27)
  PIN1(1, 0, 28, 29, 30, 31)  PIN1(1, 1, 32, 33, 34, 35)
  PIN1(1, 2, 36, 37, 38, 39)  PIN1(1, 3, 40, 41, 42, 43)
  PIN1(1, 4, 44, 45, 46, 47)  PIN1(1, 5, 48, 49, 50, 51)
  PIN1(1, 6, 52, 53, 54, 55)
  PIN1(2, 0, 56, 57, 58, 59)  PIN1(2, 1, 60, 61, 62, 63)
  PIN1(2, 2, 64, 65, 66, 67)  PIN1(2, 3, 68, 69, 70, 71)
  PIN1(2, 4, 72, 73, 74, 75)  PIN1(2, 5, 76, 77, 78, 79)
  PIN1(2, 6, 80, 81, 82, 83)
  asm volatile("s_nop 7\n\ts_nop 7");

  f32x4 zero4 = {0.f, 0.f, 0.f, 0.f};
  asm volatile("" : "+v"(zero4));

  int haddr[NT];
#pragma unroll
  for (int i = 0; i < NT; ++i) {
    const int tile = (i < NREG) ? rbase + i : lfirst + (i - NREG);
    const int j = tile * 4 + krow;
    haddr[i] = (j >> 5) * 512 + (bcol | (((j >> 3) & 3) << 4)) * 8 + (j & 7);
  }
  float c[NT], hold[NT];
#pragma unroll
  for (int i = 0; i < NT; ++i) { c[i] = 0.f; hold[i] = 0.f; }

  const int jb = rbase * 4 + krow;
  const int jl = lfirst * 4 + krow;
  int t_prev = 0, cur = 0;

  for (int s = 0; s < T_STEPS; ++s) {
    const int t = dir ? (T_STEPS - 1 - s) : s;

    short8 bf[NKT];
#pragma unroll
    for (int kt = 0; kt < NKT; ++kt)
      bf[kt] = *(const short8*)&h_lds[cur * HBUF + kt * 512 + lane * 8];

    const int sn = (s + 1 < T_STEPS) ? s + 1 : s;
    float xn = 0.f;
    if (xw) xn = x[(size_t)(dir ? T_STEPS - 1 - sn : sn) * BATCH + b0 + bcol];

    // previous step's batch-partials: plain stores to block-private lines
    if (s > 0 && bcol == 15) {
      float* hp = hpart + ((size_t)t_prev * 64 + blk) * 200;
#pragma unroll
      for (int i = 0; i < NREG; ++i) hp[jb + 4 * i] = hold[i];
#pragma unroll
      for (int i = 0; i < NLDS; ++i) hp[jl + 4 * i] = hold[NREG + i];
    }

    ushort_t* hnext = h_lds + (cur ^ 1) * HBUF;

    // ==== PHASE 1: ALL MFMA issue ====
    // AGPR region: ONE asm block, 21 MFMAs, 3 chains interleaved
    f32x4 a0, a1, a2;
    asm volatile(
      "s_nop 1\n\t"
      "v_mfma_f32_16x16x32_bf16 %0, a[0:3],    %3, %10\n\t"
      "v_mfma_f32_16x16x32_bf16 %1, a[28:31],  %3, %10\n\t"
      "v_mfma_f32_16x16x32_bf16 %2, a[56:59],  %3, %10\n\t"
      "v_mfma_f32_16x16x32_bf16 %0, a[4:7],    %4, %0\n\t"
      "v_mfma_f32_16x16x32_bf16 %1, a[32:35],  %4, %1\n\t"
      "v_mfma_f32_16x16x32_bf16 %2, a[60:63],  %4, %2\n\t"
      "v_mfma_f32_16x16x32_bf16 %0, a[8:11],   %5, %0\n\t"
      "v_mfma_f32_16x16x32_bf16 %1, a[36:39],  %5, %1\n\t"
      "v_mfma_f32_16x16x32_bf16 %2, a[64:67],  %5, %2\n\t"
      "v_mfma_f32_16x16x32_bf16 %0, a[12:15],  %6, %0\n\t"
      "v_mfma_f32_16x16x32_bf16 %1, a[40:43],  %6, %1\n\t"
      "v_mfma_f32_16x16x32_bf16 %2, a[68:71],  %6, %2\n\t"
      "v_mfma_f32_16x16x32_bf16 %0, a[16:19],  %7, %0\n\t"
      "v_mfma_f32_16x16x32_bf16 %1, a[44:47],  %7, %1\n\t"
      "v_mfma_f32_16x16x32_bf16 %2, a[72:75],  %7, %2\n\t"
      "v_mfma_f32_16x16x32_bf16 %0, a[20:23],  %8, %0\n\t"
      "v_mfma_f32_16x16x32_bf16 %1, a[48:51],  %8, %1\n\t"
      "v_mfma_f32_16x16x32_bf16 %2, a[76:79],  %8, %2\n\t"
      "v_mfma_f32_16x16x32_bf16 %0, a[24:27],  %9, %0\n\t"
      "v_mfma_f32_16x16x32_bf16 %1, a[52:55],  %9, %1\n\t"
      "v_mfma_f32_16x16x32_bf16 %2, a[80:83],  %9, %2\n\t"
      "s_nop 7\n\ts_nop 7"
      : "=&v"(a0), "=&v"(a1), "=&v"(a2)
      : "v"(bf[0]), "v"(bf[1]), "v"(bf[2]), "v"(bf[3]), "v"(bf[4]),
        "v"(bf[5]), "v"(bf[6]), "v"(zero4)
      : ACLOB);

    // LDS-tile chains (issue now, consume in phase 2)
    f32x4 bl[NLDS];
    if constexpr (NLDS == 1) {
      {
        const short8 af = *(const short8*)&w_lds_my[0 * 512 + lane * 8];
        asm volatile("s_nop 1\n\t"
                     "v_mfma_f32_16x16x32_bf16 %0, %1, %2, %3"
                     : "=&v"(bl[0]) : "v"(af), "v"(bf[0]), "v"(zero4));
      }
#pragma unroll
      for (int kt = 1; kt < NKT - 1; ++kt) {
        const short8 af = *(const short8*)&w_lds_my[kt * 512 + lane * 8];
        asm volatile("v_mfma_f32_16x16x32_bf16 %0, %1, %2, %0"
                     : "+v"(bl[0]) : "v"(af), "v"(bf[kt]));
      }
      {
        const short8 af = *(const short8*)&w_lds_my[6 * 512 + lane * 8];
        asm volatile("v_mfma_f32_16x16x32_bf16 %0, %1, %2, %0\n\t"
                     "s_nop 7\n\ts_nop 7"
                     : "+v"(bl[0]) : "v"(af), "v"(bf[6]));
      }
    } else {  // NLDS == 2
      {
        const short8 af0 = *(const short8*)&w_lds_my[(0 * NKT + 0) * 512 + lane * 8];
        const short8 af1 = *(const short8*)&w_lds_my[(1 * NKT + 0) * 512 + lane * 8];
        asm volatile("s_nop 1\n\t"
                     "v_mfma_f32_16x16x32_bf16 %0, %2, %4, %5\n\t"
                     "v_mfma_f32_16x16x32_bf16 %1, %3, %4, %5"
                     : "=&v"(bl[0]), "=&v"(bl[1])
                     : "v"(af0), "v"(af1), "v"(bf[0]), "v"(zero4));
      }
#pragma unroll
      for (int kt = 1; kt < NKT - 1; ++kt) {
        const short8 af0 = *(const short8*)&w_lds_my[(0 * NKT + kt) * 512 + lane * 8];
        const short8 af1 = *(const short8*)&w_lds_my[(1 * NKT + kt) * 512 + lane * 8];
        asm volatile("v_mfma_f32_16x16x32_bf16 %0, %2, %4, %0\n\t"
                     "v_mfma_f32_16x16x32_bf16 %1, %3, %4, %1"
                     : "+v"(bl[0]), "+v"(bl[1])
                     : "v"(af0), "v"(af1), "v"(bf[kt]));
      }
      {
        const short8 af0 = *(const short8*)&w_lds_my[(0 * NKT + 6) * 512 + lane * 8];
        const short8 af1 = *(const short8*)&w_lds_my[(1 * NKT + 6) * 512 + lane * 8];
        asm volatile("v_mfma_f32_16x16x32_bf16 %0, %2, %4, %0\n\t"
                     "v_mfma_f32_16x16x32_bf16 %1, %3, %4, %1\n\t"
                     "s_nop 7\n\ts_nop 7"
                     : "+v"(bl[0]), "+v"(bl[1])
                     : "v"(af0), "v"(af1), "v"(bf[6]));
      }
    }

    // ==== PHASE 2: ALL cell updates (4-5 independent trans chains) ====
    cell_update(a0, haddr[0], hnext, c[0], hold[0]);
    cell_update(a1, haddr[1], hnext, c[1], hold[1]);
    cell_update(a2, haddr[2], hnext, c[2], hold[2]);
#pragma unroll
    for (int i = 0; i < NLDS; ++i)
      cell_update(bl[i], haddr[NREG + i], hnext, c[NREG + i], hold[NREG + i]);

    // x(t+1) slots last
    if (xw) {
      const ushort_t hi = f2bf(xn);
      const ushort_t lo = f2bf(xn - bf2f(hi));
      const int sb = 6 * 512 + lane * 8;
      hnext[sb + 2] = hi;
      hnext[sb + 3] = hi;
      hnext[sb + 4] = lo;
    }

    t_prev = t;
    asm volatile("s_waitcnt lgkmcnt(0)\n\ts_barrier" ::: "memory");
    cur ^= 1;
  }
  if (bcol == 15) {
    float* hp = hpart + ((size_t)t_prev * 64 + blk) * 200;
#pragma unroll
    for (int i = 0; i < NREG; ++i) hp[jb + 4 * i] = hold[i];
#pragma unroll
    for (int i = 0; i < NLDS; ++i) hp[jl + 4 * i] = hold[NREG + i];
  }
}

// ---------------------------------------------------------------------------
// main scan kernel: 64 blocks, 768 threads, 3 waves/SIMD (84 AGPR + ~86 arch)
// ---------------------------------------------------------------------------
__global__ __launch_bounds__(THREADS, 3) void lstm_main(
    const float* __restrict__ x, const ushort_t* __restrict__ w_sw,
    float* __restrict__ hpart) {
  extern __shared__ __align__(16) ushort_t dynlds[];
  ushort_t* h_lds = dynlds;
  ushort_t* w_lds = dynlds + 2 * HBUF;

  const int tid = threadIdx.x;
  const int lane = tid & 63;
  const int wv = tid >> 6;          // 0..11
  const int blk = blockIdx.x;
  const int dir = blk & 1;
  const int b0 = (blk >> 1) * 16;

  const ushort_t* wg = w_sw + (size_t)dir * NMT * NKT * 512;

  for (int i = tid; i < HBUF; i += THREADS) ((unsigned*)h_lds)[i] = 0;
  // stage LDS weight tiles 36..49
  for (int i = tid; i < NLDST * NKT * 64; i += THREADS)
    *(short8*)&w_lds[(size_t)i * 8] =
        *(const short8*)(wg + (size_t)36 * NKT * 512 + (size_t)i * 8);
  __syncthreads();

  if (tid < 16) {
    const int t0 = dir ? T_STEPS - 1 : 0;
    const float x0 = x[(size_t)t0 * BATCH + b0 + tid];
    const ushort_t hi = f2bf(x0);
    const ushort_t lo = f2bf(x0 - bf2f(hi));
    const int sb = 6 * 512 + (16 + tid) * 8;
    h_lds[sb + 0] = 0x3F80; h_lds[sb + 1] = 0x3F80;
    h_lds[HBUF + sb + 0] = 0x3F80; h_lds[HBUF + sb + 1] = 0x3F80;
    h_lds[sb + 2] = hi; h_lds[sb + 3] = hi; h_lds[sb + 4] = lo;
  }
  __syncthreads();

  // wave w: AGPR tiles 3w..3w+2 (0..35); LDS tiles: w<10 -> {36+w},
  // w==10 -> {46,47}, w==11 -> {48,49}
  const int rbase = 3 * wv;
  if (wv < 10) {
    scan_loop<1>(rbase, 36 + wv, dir, b0, lane, wv, blk, wg, x, hpart, h_lds,
                 w_lds + (size_t)wv * NKT * 512);
  } else if (wv == 10) {
    scan_loop<2>(rbase, 46, dir, b0, lane, wv, blk, wg, x, hpart, h_lds,
                 w_lds + (size_t)10 * NKT * 512);
  } else {
    scan_loop<2>(rbase, 48, dir, b0, lane, wv, blk, wg, x, hpart, h_lds,
                 w_lds + (size_t)12 * NKT * 512);
  }
}

// ---------------------------------------------------------------------------
__global__ void out_proj(const float* __restrict__ hpart, const float* __restrict__ Wfc,
                         const float* __restrict__ bfc, float* __restrict__ out) {
  const int t = blockIdx.x, tid = threadIdx.x;
  const float* hb = hpart + (size_t)t * 64 * 200;
  float a[10] = {0.f, 0.f, 0.f, 0.f, 0.f, 0.f, 0.f, 0.f, 0.f, 0.f};
  for (int col = tid; col < 400; col += 256) {
    const int dir = (col >= HID) ? 1 : 0;
    const int j = col - dir * HID;
    float s = 0.f;
#pragma unroll
    for (int sl = 0; sl < 32; ++sl) s += hb[(size_t)((sl << 1) | dir) * 200 + j];
    const float hv = s * (1.f / 512.f);
#pragma unroll
    for (int o = 0; o < 10; ++o) a[o] = fmaf(hv, Wfc[o * 400 + col], a[o]);
  }
#pragma unroll
  for (int o = 0; o < 10; ++o) {
    float v = a[o];
    for (int m = 32; m; m >>= 1) v += __shfl_xor(v, m);
    a[o] = v;
  }
  __shared__ float red[4][10];
  if ((tid & 63) == 0)
#pragma unroll
    for (int o = 0; o < 10; ++o) red[tid >> 6][o] = a[o];
  __syncthreads();
  if (tid < 10)
    out[t * 10 + tid] = bfc[tid] + red[0][tid] + red[1][tid] + red[2][tid] + red[3][tid];
}

extern "C" void kernel_launch(void* const* d_in, const int* in_sizes, int n_in,
                              void* d_out, int out_size, void* d_ws, size_t ws_size,
                              hipStream_t stream) {
  const float* x     = (const float*)d_in[0];
  const float* W_in  = (const float*)d_in[1];
  const float* b_in  = (const float*)d_in[2];
  const float* Wih_f = (const float*)d_in[3];
  const float* Whh_f = (const float*)d_in[4];
  const float* b_f   = (const float*)d_in[5];
  const float* Wih_b = (const float*)d_in[6];
  const float* Whh_b = (const float*)d_in[7];
  const float* b_b   = (const float*)d_in[8];
  const float* W_fc  = (const float*)d_in[9];
  const float* b_fc  = (const float*)d_in[10];
  float* out = (float*)d_out;

  char* ws = (char*)d_ws;
  float*    hpart = (float*)(ws + WS_HPART);
  float*    uv_g  = (float*)(ws + WS_UV);
  ushort_t* w_sw  = (ushort_t*)(ws + WS_WSW);

  hipFuncSetAttribute((const void*)lstm_main,
                      hipFuncAttributeMaxDynamicSharedMemorySize, DYN_LDS);

  prep_uv<<<2, 256, 0, stream>>>(Wih_f, b_f, Wih_b, b_b, W_in, b_in, uv_g);
  prep_w<<<2 * NMT * NKT, 64, 0, stream>>>(Whh_f, Whh_b, uv_g, w_sw);
  lstm_main<<<64, THREADS, DYN_LDS, stream>>>(x, w_sw, hpart);
  out_proj<<<T_STEPS, 256, 0, stream>>>(hpart, W_fc, b_fc, out);
}

// Round 21
// 1405.368 us; speedup vs baseline: 1.3788x; 1.3788x over previous
//
#include <hip/hip_runtime.h>

// ---------------------------------------------------------------------------
// BiLSTM (T=784, B=512, H=200, D=1) on MI355X — round 21 (revert to r17 best).
//
// r19/r20 post-mortem: both LDS-read-reduction variants (6-chain merged, and
// 5-chain AGPR-only under phase-split) hit RA infeasibility: with >=140 AGPR
// clobbers, PHASE-SPLIT keeps bf[7]+all accumulators live across the whole
// MFMA region, so whole-region pressure (not just in-asm live) exceeds the
// arch budget. Abandoning that axis; reverting to the proven best (r17):
//  * 64 blocks (dir, 16-batch slice), 512 thr, 2 waves/SIMD.
//  * 4 AGPR tiles/wave (a0..a111, 112 clobbers -> 144 arch budget) + 18 LDS
//    tiles; ONE 28-MFMA 4-chain asm block (>=4-chain ILP rule).
//  * PHASE-SPLIT: all MFMA issue first, then all 6-7 cell chains (the -14%
//    structural win of r17).
//  * prescaled exp2-ready weights, v_cvt_pk_bf16_f32, block-private
//    fire-and-forget hpart stores, lgkm-only barrier, input path folded
//    into K-pad slots 200..204, gate-interleaved M.
// Measured r17: 1409us, absmax 4.8828e-4, MfmaUtil 8.2, VALUBusy 12.1.
// ---------------------------------------------------------------------------

typedef short short8 __attribute__((ext_vector_type(8)));
typedef float f32x4 __attribute__((ext_vector_type(4)));
typedef unsigned short ushort_t;

#define T_STEPS 784
#define BATCH   512
#define HID     200
#define NKT     7
#define NMT     50
#define THREADS 512
#define HBUF    3584
#define NLDST   18
#define DYN_LDS (2 * HBUF * 2 + NLDST * NKT * 512 * 2)  // 143360 B

// ws layout (bytes)
#define WS_HPART 0                                       // 784*64*200*4
#define WS_UV    (40140800)                              // 12,800
#define WS_WSW   (40140800 + 12800)                      // 716,800

#define ACLOB \
  "a0","a1","a2","a3","a4","a5","a6","a7","a8","a9","a10","a11","a12","a13", \
  "a14","a15","a16","a17","a18","a19","a20","a21","a22","a23","a24","a25",   \
  "a26","a27","a28","a29","a30","a31","a32","a33","a34","a35","a36","a37",   \
  "a38","a39","a40","a41","a42","a43","a44","a45","a46","a47","a48","a49",   \
  "a50","a51","a52","a53","a54","a55","a56","a57","a58","a59","a60","a61",   \
  "a62","a63","a64","a65","a66","a67","a68","a69","a70","a71","a72","a73",   \
  "a74","a75","a76","a77","a78","a79","a80","a81","a82","a83","a84","a85",   \
  "a86","a87","a88","a89","a90","a91","a92","a93","a94","a95","a96","a97",   \
  "a98","a99","a100","a101","a102","a103","a104","a105","a106","a107",       \
  "a108","a109","a110","a111"

#define L1E 1.44269504088896340736f  // log2(e)

__device__ __forceinline__ ushort_t f2bf(float f) {
  union { float f; unsigned u; } x; x.f = f;
  return (ushort_t)((x.u + 0x7FFFu + ((x.u >> 16) & 1u)) >> 16);  // RNE
}
__device__ __forceinline__ float bf2f(ushort_t u) {
  union { unsigned u; float f; } x; x.u = (unsigned)u << 16; return x.f;
}

__device__ __forceinline__ float row16_sum(float v) {
  union { float f; int i; } a, b;
  a.f = v;
  b.i = __builtin_amdgcn_update_dpp(0, a.i, 0x118, 0xF, 0xF, true); a.f += b.f;
  b.i = __builtin_amdgcn_update_dpp(0, a.i, 0x114, 0xF, 0xF, true); a.f += b.f;
  b.i = __builtin_amdgcn_update_dpp(0, a.i, 0x112, 0xF, 0xF, true); a.f += b.f;
  b.i = __builtin_amdgcn_update_dpp(0, a.i, 0x111, 0xF, 0xF, true); a.f += b.f;
  return a.f;  // row sum valid at bcol==15
}

// --- AGPR pin: one 4-dword fragment of tile T, k-tile K into fixed a-regs
#define PIN1(T, K, N0, N1, N2, N3)                                            \
  {                                                                           \
    union { short8 s; unsigned u[4]; } cv;                                    \
    cv.s = *(const short8*)(wg +                                              \
        ((size_t)((rbase + (T)) * NKT + (K))) * 512 + lane * 8);              \
    asm volatile("v_accvgpr_write_b32 a" #N0 ", %0\n\t"                       \
                 "v_accvgpr_write_b32 a" #N1 ", %1\n\t"                       \
                 "v_accvgpr_write_b32 a" #N2 ", %2\n\t"                       \
                 "v_accvgpr_write_b32 a" #N3 ", %3"                           \
                 :: "v"(cv.u[0]), "v"(cv.u[1]), "v"(cv.u[2]), "v"(cv.u[3])    \
                 : "a" #N0, "a" #N1, "a" #N2, "a" #N3);                       \
  }

// ---------------------------------------------------------------------------
__global__ void prep_uv(const float* __restrict__ Wih_f, const float* __restrict__ b_f,
                        const float* __restrict__ Wih_b, const float* __restrict__ b_b,
                        const float* __restrict__ W_in, const float* __restrict__ b_in,
                        float* __restrict__ uv_g) {
  const int dir = blockIdx.x, j = threadIdx.x;
  if (j >= HID) return;
  const float* Wih = dir ? Wih_b : Wih_f;
  const float* b   = dir ? b_b   : b_f;
  for (int q = 0; q < 4; ++q) {
    const int row = q * HID + j;
    const float* wr = Wih + (size_t)row * HID;
    float u = 0.f, v = 0.f;
    for (int k = 0; k < HID; ++k) {
      u = fmaf(wr[k], W_in[k], u);
      v = fmaf(wr[k], b_in[k], v);
    }
    uv_g[(size_t)dir * 1600 + j * 8 + q]     = u;
    uv_g[(size_t)dir * 1600 + j * 8 + 4 + q] = v + b[row];
  }
}

// ---------------------------------------------------------------------------
// prep_w: A-fragments, rows pre-scaled by sq = (q==2) ? -2*log2e : -log2e.
// ---------------------------------------------------------------------------
__global__ void prep_w(const float* __restrict__ Whh_f, const float* __restrict__ Whh_b,
                       const float* __restrict__ uv_g, ushort_t* __restrict__ w_sw) {
  const int bid = blockIdx.x, lane = threadIdx.x;
  const int dir = bid / (NMT * NKT);
  const int rem = bid % (NMT * NKT);
  const int mt = rem / NKT, kt = rem % NKT;
  const float* W = dir ? Whh_b : Whh_f;
  const int m = lane & 15;
  const int q = m & 3;
  const int j = mt * 4 + (m >> 2);
  const int row = q * HID + j;
  const int grp = lane >> 4;
  const float sq = (q == 2) ? (-2.f * L1E) : (-L1E);
  short8 v8 = {0, 0, 0, 0, 0, 0, 0, 0};
  if (kt < 6) {
#pragma unroll
    for (int e = 0; e < 8; ++e)
      v8[e] = (short)f2bf(sq * W[(size_t)row * HID + kt * 32 + grp * 8 + e]);
  } else if (grp == 0) {
#pragma unroll
    for (int e = 0; e < 8; ++e)
      v8[e] = (short)f2bf(sq * W[(size_t)row * HID + 192 + e]);
  } else if (grp == 1) {
    const float U = sq * uv_g[(size_t)dir * 1600 + j * 8 + q];
    const float V = sq * uv_g[(size_t)dir * 1600 + j * 8 + 4 + q];
    const ushort_t vhi = f2bf(V), uhi = f2bf(U);
    v8[0] = (short)vhi;
    v8[1] = (short)f2bf(V - bf2f(vhi));
    v8[2] = (short)uhi;
    v8[3] = (short)f2bf(U - bf2f(uhi));
    v8[4] = (short)uhi;
  }
  *(short8*)(w_sw + (size_t)bid * 512 + (size_t)lane * 8) = v8;
}

// ---------------------------------------------------------------------------
// cell update: a[0..3] arrive PRE-SCALED exp2-ready. ec clamp kept.
// ---------------------------------------------------------------------------
__device__ __forceinline__ void cell_update(const f32x4 a, const int haddr,
                                            ushort_t* __restrict__ hnext,
                                            float& c, float& hold) {
  const float ei = __builtin_amdgcn_exp2f(a[0]);
  const float ef = __builtin_amdgcn_exp2f(a[1]);
  const float eg = __builtin_amdgcn_exp2f(a[2]);
  const float eo = __builtin_amdgcn_exp2f(a[3]);
  const float pi = 1.f + ei, pf = 1.f + ef, pg = 1.f + eg;
  const float pig = pi * pg;
  const float R1 = __builtin_amdgcn_rcpf(pig * pf);
  const float sf = pig * R1;
  const float sitg = (1.f - eg) * pf * R1;
  const float cn = fmaf(sf, c, sitg);
  c = cn;
  const float ec = __builtin_amdgcn_exp2f(fminf(-2.f * L1E * cn, 83.f));
  const float R2 = __builtin_amdgcn_rcpf((1.f + ec) * (1.f + eo));
  const float h = (1.f - ec) * R2;
  unsigned hu;
  asm("v_cvt_pk_bf16_f32 %0, %1, %2" : "=v"(hu) : "v"(h), "v"(0.f));
  hnext[haddr] = (ushort_t)hu;
  hold = row16_sum(h);
}

// ---------------------------------------------------------------------------
// 784-step scan: ALL MFMA issue first (AGPR block + LDS chains), then ALL
// cell_updates together (6-7 way ILP across independent trans chains).
// ---------------------------------------------------------------------------
template <int NLDS>
__device__ __forceinline__ void scan_loop(
    const int rbase, const int lfirst, const int dir, const int b0,
    const int lane, const int wv, const int blk, const ushort_t* __restrict__ wg,
    const float* __restrict__ x, float* __restrict__ hpart,
    ushort_t* __restrict__ h_lds, const ushort_t* __restrict__ w_lds_my) {
  constexpr int NREG = 4;
  constexpr int NT = NREG + NLDS;
  const int bcol = lane & 15, krow = lane >> 4;
  const bool xw = (wv == 0) & (krow == 1);

  PIN1(0, 0,  0,  1,  2,  3)  PIN1(0, 1,  4,  5,  6,  7)
  PIN1(0, 2,  8,  9, 10, 11)  PIN1(0, 3, 12, 13, 14, 15)
  PIN1(0, 4, 16, 17, 18, 19)  PIN1(0, 5, 20, 21, 22, 23)
  PIN1(0, 6, 24, 25, 26, 27)
  PIN1(1, 0, 28, 29, 30, 31)  PIN1(1, 1, 32, 33, 34, 35)
  PIN1(1, 2, 36, 37, 38, 39)  PIN1(1, 3, 40, 41, 42, 43)
  PIN1(1, 4, 44, 45, 46, 47)  PIN1(1, 5, 48, 49, 50, 51)
  PIN1(1, 6, 52, 53, 54, 55)
  PIN1(2, 0, 56, 57, 58, 59)  PIN1(2, 1, 60, 61, 62, 63)
  PIN1(2, 2, 64, 65, 66, 67)  PIN1(2, 3, 68, 69, 70, 71)
  PIN1(2, 4, 72, 73, 74, 75)  PIN1(2, 5, 76, 77, 78, 79)
  PIN1(2, 6, 80, 81, 82, 83)
  PIN1(3, 0, 84, 85, 86, 87)  PIN1(3, 1, 88, 89, 90, 91)
  PIN1(3, 2, 92, 93, 94, 95)  PIN1(3, 3, 96, 97, 98, 99)
  PIN1(3, 4, 100, 101, 102, 103)  PIN1(3, 5, 104, 105, 106, 107)
  PIN1(3, 6, 108, 109, 110, 111)
  asm volatile("s_nop 7\n\ts_nop 7");

  f32x4 zero4 = {0.f, 0.f, 0.f, 0.f};
  asm volatile("" : "+v"(zero4));

  int haddr[NT];
#pragma unroll
  for (int i = 0; i < NT; ++i) {
    const int tile = (i < NREG) ? rbase + i : lfirst + (i - NREG);
    const int j = tile * 4 + krow;
    haddr[i] = (j >> 5) * 512 + (bcol | (((j >> 3) & 3) << 4)) * 8 + (j & 7);
  }
  float c[NT], hold[NT];
#pragma unroll
  for (int i = 0; i < NT; ++i) { c[i] = 0.f; hold[i] = 0.f; }

  const int jb = rbase * 4 + krow;
  const int jl = lfirst * 4 + krow;
  int t_prev = 0, cur = 0;

  for (int s = 0; s < T_STEPS; ++s) {
    const int t = dir ? (T_STEPS - 1 - s) : s;

    short8 bf[NKT];
#pragma unroll
    for (int kt = 0; kt < NKT; ++kt)
      bf[kt] = *(const short8*)&h_lds[cur * HBUF + kt * 512 + lane * 8];

    const int sn = (s + 1 < T_STEPS) ? s + 1 : s;
    float xn = 0.f;
    if (xw) xn = x[(size_t)(dir ? T_STEPS - 1 - sn : sn) * BATCH + b0 + bcol];

    // previous step's batch-partials: plain stores to block-private lines
    if (s > 0 && bcol == 15) {
      float* hp = hpart + ((size_t)t_prev * 64 + blk) * 200;
#pragma unroll
      for (int i = 0; i < NREG; ++i) hp[jb + 4 * i] = hold[i];
#pragma unroll
      for (int i = 0; i < NLDS; ++i) hp[jl + 4 * i] = hold[NREG + i];
    }

    ushort_t* hnext = h_lds + (cur ^ 1) * HBUF;

    // ==== PHASE 1: ALL MFMA issue ====
    // AGPR region: ONE asm block, 28 MFMAs, 4 chains interleaved
    f32x4 a0, a1, a2, a3;
    asm volatile(
      "s_nop 1\n\t"
      "v_mfma_f32_16x16x32_bf16 %0, a[0:3],    %4, %11\n\t"
      "v_mfma_f32_16x16x32_bf16 %1, a[28:31],  %4, %11\n\t"
      "v_mfma_f32_16x16x32_bf16 %2, a[56:59],  %4, %11\n\t"
      "v_mfma_f32_16x16x32_bf16 %3, a[84:87],  %4, %11\n\t"
      "v_mfma_f32_16x16x32_bf16 %0, a[4:7],    %5, %0\n\t"
      "v_mfma_f32_16x16x32_bf16 %1, a[32:35],  %5, %1\n\t"
      "v_mfma_f32_16x16x32_bf16 %2, a[60:63],  %5, %2\n\t"
      "v_mfma_f32_16x16x32_bf16 %3, a[88:91],  %5, %3\n\t"
      "v_mfma_f32_16x16x32_bf16 %0, a[8:11],   %6, %0\n\t"
      "v_mfma_f32_16x16x32_bf16 %1, a[36:39],  %6, %1\n\t"
      "v_mfma_f32_16x16x32_bf16 %2, a[64:67],  %6, %2\n\t"
      "v_mfma_f32_16x16x32_bf16 %3, a[92:95],  %6, %3\n\t"
      "v_mfma_f32_16x16x32_bf16 %0, a[12:15],  %7, %0\n\t"
      "v_mfma_f32_16x16x32_bf16 %1, a[40:43],  %7, %1\n\t"
      "v_mfma_f32_16x16x32_bf16 %2, a[68:71],  %7, %2\n\t"
      "v_mfma_f32_16x16x32_bf16 %3, a[96:99],  %7, %3\n\t"
      "v_mfma_f32_16x16x32_bf16 %0, a[16:19],  %8, %0\n\t"
      "v_mfma_f32_16x16x32_bf16 %1, a[44:47],  %8, %1\n\t"
      "v_mfma_f32_16x16x32_bf16 %2, a[72:75],  %8, %2\n\t"
      "v_mfma_f32_16x16x32_bf16 %3, a[100:103],%8, %3\n\t"
      "v_mfma_f32_16x16x32_bf16 %0, a[20:23],  %9, %0\n\t"
      "v_mfma_f32_16x16x32_bf16 %1, a[48:51],  %9, %1\n\t"
      "v_mfma_f32_16x16x32_bf16 %2, a[76:79],  %9, %2\n\t"
      "v_mfma_f32_16x16x32_bf16 %3, a[104:107],%9, %3\n\t"
      "v_mfma_f32_16x16x32_bf16 %0, a[24:27],  %10, %0\n\t"
      "v_mfma_f32_16x16x32_bf16 %1, a[52:55],  %10, %1\n\t"
      "v_mfma_f32_16x16x32_bf16 %2, a[80:83],  %10, %2\n\t"
      "v_mfma_f32_16x16x32_bf16 %3, a[108:111],%10, %3\n\t"
      "s_nop 7\n\ts_nop 7"
      : "=&v"(a0), "=&v"(a1), "=&v"(a2), "=&v"(a3)
      : "v"(bf[0]), "v"(bf[1]), "v"(bf[2]), "v"(bf[3]), "v"(bf[4]),
        "v"(bf[5]), "v"(bf[6]), "v"(zero4)
      : ACLOB);

    // LDS-tile chains (issue now, consume after): NLDS accumulators
    f32x4 bl[NLDS];
    if constexpr (NLDS == 2) {
      {
        const short8 af0 = *(const short8*)&w_lds_my[(0 * NKT + 0) * 512 + lane * 8];
        const short8 af1 = *(const short8*)&w_lds_my[(1 * NKT + 0) * 512 + lane * 8];
        asm volatile("s_nop 1\n\t"
                     "v_mfma_f32_16x16x32_bf16 %0, %2, %4, %5\n\t"
                     "v_mfma_f32_16x16x32_bf16 %1, %3, %4, %5"
                     : "=&v"(bl[0]), "=&v"(bl[1])
                     : "v"(af0), "v"(af1), "v"(bf[0]), "v"(zero4));
      }
#pragma unroll
      for (int kt = 1; kt < NKT - 1; ++kt) {
        const short8 af0 = *(const short8*)&w_lds_my[(0 * NKT + kt) * 512 + lane * 8];
        const short8 af1 = *(const short8*)&w_lds_my[(1 * NKT + kt) * 512 + lane * 8];
        asm volatile("v_mfma_f32_16x16x32_bf16 %0, %2, %4, %0\n\t"
                     "v_mfma_f32_16x16x32_bf16 %1, %3, %4, %1"
                     : "+v"(bl[0]), "+v"(bl[1])
                     : "v"(af0), "v"(af1), "v"(bf[kt]));
      }
      {
        const short8 af0 = *(const short8*)&w_lds_my[(0 * NKT + 6) * 512 + lane * 8];
        const short8 af1 = *(const short8*)&w_lds_my[(1 * NKT + 6) * 512 + lane * 8];
        asm volatile("v_mfma_f32_16x16x32_bf16 %0, %2, %4, %0\n\t"
                     "v_mfma_f32_16x16x32_bf16 %1, %3, %4, %1\n\t"
                     "s_nop 7\n\ts_nop 7"
                     : "+v"(bl[0]), "+v"(bl[1])
                     : "v"(af0), "v"(af1), "v"(bf[6]));
      }
    } else {  // NLDS == 3
      {
        const short8 af0 = *(const short8*)&w_lds_my[(0 * NKT + 0) * 512 + lane * 8];
        const short8 af1 = *(const short8*)&w_lds_my[(1 * NKT + 0) * 512 + lane * 8];
        const short8 af2 = *(const short8*)&w_lds_my[(2 * NKT + 0) * 512 + lane * 8];
        asm volatile("s_nop 1\n\t"
                     "v_mfma_f32_16x16x32_bf16 %0, %3, %6, %7\n\t"
                     "v_mfma_f32_16x16x32_bf16 %1, %4, %6, %7\n\t"
                     "v_mfma_f32_16x16x32_bf16 %2, %5, %6, %7"
                     : "=&v"(bl[0]), "=&v"(bl[1]), "=&v"(bl[2])
                     : "v"(af0), "v"(af1), "v"(af2), "v"(bf[0]), "v"(zero4));
      }
#pragma unroll
      for (int kt = 1; kt < NKT - 1; ++kt) {
        const short8 af0 = *(const short8*)&w_lds_my[(0 * NKT + kt) * 512 + lane * 8];
        const short8 af1 = *(const short8*)&w_lds_my[(1 * NKT + kt) * 512 + lane * 8];
        const short8 af2 = *(const short8*)&w_lds_my[(2 * NKT + kt) * 512 + lane * 8];
        asm volatile("v_mfma_f32_16x16x32_bf16 %0, %3, %6, %0\n\t"
                     "v_mfma_f32_16x16x32_bf16 %1, %4, %6, %1\n\t"
                     "v_mfma_f32_16x16x32_bf16 %2, %5, %6, %2"
                     : "+v"(bl[0]), "+v"(bl[1]), "+v"(bl[2])
                     : "v"(af0), "v"(af1), "v"(af2), "v"(bf[kt]));
      }
      {
        const short8 af0 = *(const short8*)&w_lds_my[(0 * NKT + 6) * 512 + lane * 8];
        const short8 af1 = *(const short8*)&w_lds_my[(1 * NKT + 6) * 512 + lane * 8];
        const short8 af2 = *(const short8*)&w_lds_my[(2 * NKT + 6) * 512 + lane * 8];
        asm volatile("v_mfma_f32_16x16x32_bf16 %0, %3, %6, %0\n\t"
                     "v_mfma_f32_16x16x32_bf16 %1, %4, %6, %1\n\t"
                     "v_mfma_f32_16x16x32_bf16 %2, %5, %6, %2\n\t"
                     "s_nop 7\n\ts_nop 7"
                     : "+v"(bl[0]), "+v"(bl[1]), "+v"(bl[2])
                     : "v"(af0), "v"(af1), "v"(af2), "v"(bf[6]));
      }
    }

    // ==== PHASE 2: ALL cell updates (6-7 independent trans chains) ====
    ushort_t* hn = hnext;
    cell_update(a0, haddr[0], hn, c[0], hold[0]);
    cell_update(a1, haddr[1], hn, c[1], hold[1]);
    cell_update(a2, haddr[2], hn, c[2], hold[2]);
    cell_update(a3, haddr[3], hn, c[3], hold[3]);
#pragma unroll
    for (int i = 0; i < NLDS; ++i)
      cell_update(bl[i], haddr[NREG + i], hn, c[NREG + i], hold[NREG + i]);

    // x(t+1) slots last (x-load latency hidden under the step)
    if (xw) {
      const ushort_t hi = f2bf(xn);
      const ushort_t lo = f2bf(xn - bf2f(hi));
      const int sb = 6 * 512 + lane * 8;
      hnext[sb + 2] = hi;
      hnext[sb + 3] = hi;
      hnext[sb + 4] = lo;
    }

    t_prev = t;
    asm volatile("s_waitcnt lgkmcnt(0)\n\ts_barrier" ::: "memory");
    cur ^= 1;
  }
  if (bcol == 15) {
    float* hp = hpart + ((size_t)t_prev * 64 + blk) * 200;
#pragma unroll
    for (int i = 0; i < NREG; ++i) hp[jb + 4 * i] = hold[i];
#pragma unroll
    for (int i = 0; i < NLDS; ++i) hp[jl + 4 * i] = hold[NREG + i];
  }
}

// ---------------------------------------------------------------------------
__global__ __launch_bounds__(THREADS, 2) void lstm_main(
    const float* __restrict__ x, const ushort_t* __restrict__ w_sw,
    float* __restrict__ hpart) {
  extern __shared__ __align__(16) ushort_t dynlds[];
  ushort_t* h_lds = dynlds;
  ushort_t* w_lds = dynlds + 2 * HBUF;

  const int tid = threadIdx.x;
  const int lane = tid & 63;
  const int wv = tid >> 6;
  const int blk = blockIdx.x;
  const int dir = blk & 1;
  const int b0 = (blk >> 1) * 16;

  const ushort_t* wg = w_sw + (size_t)dir * NMT * NKT * 512;

  for (int i = tid; i < HBUF; i += THREADS) ((unsigned*)h_lds)[i] = 0;
  for (int i = tid; i < NLDST * NKT * 64; i += THREADS)
    *(short8*)&w_lds[(size_t)i * 8] =
        *(const short8*)(wg + (size_t)32 * NKT * 512 + (size_t)i * 8);
  __syncthreads();

  if (tid < 16) {
    const int t0 = dir ? T_STEPS - 1 : 0;
    const float x0 = x[(size_t)t0 * BATCH + b0 + tid];
    const ushort_t hi = f2bf(x0);
    const ushort_t lo = f2bf(x0 - bf2f(hi));
    const int sb = 6 * 512 + (16 + tid) * 8;
    h_lds[sb + 0] = 0x3F80; h_lds[sb + 1] = 0x3F80;
    h_lds[HBUF + sb + 0] = 0x3F80; h_lds[HBUF + sb + 1] = 0x3F80;
    h_lds[sb + 2] = hi; h_lds[sb + 3] = hi; h_lds[sb + 4] = lo;
  }
  __syncthreads();

  const int rbase = 4 * wv;
  const int lfirst = (wv < 6) ? (32 + 2 * wv) : (44 + 3 * (wv - 6));
  const ushort_t* wl = w_lds + (size_t)(lfirst - 32) * NKT * 512;
  if (wv < 6)
    scan_loop<2>(rbase, lfirst, dir, b0, lane, wv, blk, wg, x, hpart, h_lds, wl);
  else
    scan_loop<3>(rbase, lfirst, dir, b0, lane, wv, blk, wg, x, hpart, h_lds, wl);
}

// ---------------------------------------------------------------------------
__global__ void out_proj(const float* __restrict__ hpart, const float* __restrict__ Wfc,
                         const float* __restrict__ bfc, float* __restrict__ out) {
  const int t = blockIdx.x, tid = threadIdx.x;
  const float* hb = hpart + (size_t)t * 64 * 200;
  float a[10] = {0.f, 0.f, 0.f, 0.f, 0.f, 0.f, 0.f, 0.f, 0.f, 0.f};
  for (int col = tid; col < 400; col += 256) {
    const int dir = (col >= HID) ? 1 : 0;
    const int j = col - dir * HID;
    float s = 0.f;
#pragma unroll
    for (int sl = 0; sl < 32; ++sl) s += hb[(size_t)((sl << 1) | dir) * 200 + j];
    const float hv = s * (1.f / 512.f);
#pragma unroll
    for (int o = 0; o < 10; ++o) a[o] = fmaf(hv, Wfc[o * 400 + col], a[o]);
  }
#pragma unroll
  for (int o = 0; o < 10; ++o) {
    float v = a[o];
    for (int m = 32; m; m >>= 1) v += __shfl_xor(v, m);
    a[o] = v;
  }
  __shared__ float red[4][10];
  if ((tid & 63) == 0)
#pragma unroll
    for (int o = 0; o < 10; ++o) red[tid >> 6][o] = a[o];
  __syncthreads();
  if (tid < 10)
    out[t * 10 + tid] = bfc[tid] + red[0][tid] + red[1][tid] + red[2][tid] + red[3][tid];
}

extern "C" void kernel_launch(void* const* d_in, const int* in_sizes, int n_in,
                              void* d_out, int out_size, void* d_ws, size_t ws_size,
                              hipStream_t stream) {
  const float* x     = (const float*)d_in[0];
  const float* W_in  = (const float*)d_in[1];
  const float* b_in  = (const float*)d_in[2];
  const float* Wih_f = (const float*)d_in[3];
  const float* Whh_f = (const float*)d_in[4];
  const float* b_f   = (const float*)d_in[5];
  const float* Wih_b = (const float*)d_in[6];
  const float* Whh_b = (const float*)d_in[7];
  const float* b_b   = (const float*)d_in[8];
  const float* W_fc  = (const float*)d_in[9];
  const float* b_fc  = (const float*)d_in[10];
  float* out = (float*)d_out;

  char* ws = (char*)d_ws;
  float*    hpart = (float*)(ws + WS_HPART);
  float*    uv_g  = (float*)(ws + WS_UV);
  ushort_t* w_sw  = (ushort_t*)(ws + WS_WSW);

  hipFuncSetAttribute((const void*)lstm_main,
                      hipFuncAttributeMaxDynamicSharedMemorySize, DYN_LDS);

  prep_uv<<<2, 256, 0, stream>>>(Wih_f, b_f, Wih_b, b_b, W_in, b_in, uv_g);
  prep_w<<<2 * NMT * NKT, 64, 0, stream>>>(Whh_f, Whh_b, uv_g, w_sw);
  lstm_main<<<64, THREADS, DYN_LDS, stream>>>(x, w_sw, hpart);
  out_proj<<<T_STEPS, 256, 0, stream>>>(hpart, W_fc, b_fc, out);
}